// Round 2
// baseline (325.154 us; speedup 1.0000x reference)
//
#include <hip/hip_runtime.h>

// Hidden-size-1 LSTM, B=32768 chains, 1024 open + 512 closed steps.
// R5 = R3 2-lane structure (1024 waves = 1/SIMD, the measured-best config)
// + critical-path folds. Post-R4 model: per-step wall is bound by the
// loop-carried chain z->ex2->rcp->C->ex2->rcp (~4 trans deep, ~35-40cyc
// dep latency each). Changes vs R3:
//  - h folded into next z: z = fma(rc, -2W*ro, fma(ro,W,Cc)); the
//    ro-terms compute during the eC/rcp latency window, removing the
//    h-FMA from the loop-carried path. Stored h (preds) computed
//    off-path with the bit-identical R3 formula fma(-rc, ro+ro, ro).
//  - even-lane-local t = sigma(i)*g2 before broadcast: 3 DPPs (t, rf, ro)
//    instead of 4, one fewer trans->DPP hazard.
//  - preds accumulated in regs, one even-lane ds_write_b128 per 4 steps
//    (pb stride 68, 16B-aligned rows) instead of per-step b32 writes.
//  - init (rc=0, ro=h0) makes the folded first step bit-equal to R3's.
// sigma(z) = rcp(1+exp2(-L2E*z)); tanh(z) = 1 - 2*rcp(1+exp2(2*L2E*z)).
// c pre-scaled: C = 2*log2(e)*c.

#define L2E 1.44269504088896340736f
#define B_TOT 32768
#define T_IN 1024
#define STEPS 512
#define CPB 32          // chains per block (one wave, 2 lanes/chain)
#define CH 64           // chunk length in steps
#define PAD 65          // sb stride: stage-write 2-way max, step reads conflict-free
#define PPAD 68         // pb stride: rows 16B-aligned for b128 pred writes

__device__ __forceinline__ float ex2(float x){ return __builtin_amdgcn_exp2f(x); }
__device__ __forceinline__ float rcp(float x){ return __builtin_amdgcn_rcpf(x); }
template<int CTRL>
__device__ __forceinline__ float qp(float v){
    // quad_perm broadcast within each lane pair:
    // 0xA0 -> even member's value to both; 0xF5 -> odd member's value to both
    return __int_as_float(__builtin_amdgcn_mov_dpp(__float_as_int(v), CTRL, 0xF, 0xF, true));
}

// even lane: gate1 = i (-L2E scale), gate2 = g (+2*L2E scale)
// odd  lane: gate1 = f,              gate2 = o
struct LaneK { float A1,B1,C1, A2,B2,C2, W1,W2, B1m2,B2m2, W1m2,W2m2; };

// state carried on the critical path: rc (=rcp(1+2^C)), ro (=sigma(o)), C
__device__ __forceinline__ void tail2(float z1, float z2, float& rc, float& ro, float& C){
    float e1 = ex2(z1);
    float e2 = ex2(z2);
    float r1 = rcp(1.0f + e1);
    float r2 = rcp(1.0f + e2);
    // even-local: g2 = 2*L2E*tanh(g), t = sigma(i)*g2 (garbage on odd, unused)
    float g2 = fmaf(r2, -4.0f * L2E, 2.0f * L2E);
    float t  = r1 * g2;
    float tb = qp<0xA0>(t);       // even member's t to both lanes
    float rf = qp<0xF5>(r1);      // sigma(zf)
    ro       = qp<0xF5>(r2);      // sigma(zo)
    C  = fmaf(rf, C, tb);         // C = 2*L2E*c_new
    float eC = ex2(C);
    rc = rcp(1.0f + eC);
}

// one open-loop step: z = A*x + B*h + C with h = ro*(1-2rc) folded in
#define OSTEP(xv) do{                                                   \
    float xp1 = fmaf((xv), K.A1, K.C1), xp2 = fmaf((xv), K.A2, K.C2);   \
    float w1  = fmaf(ro, K.B1, xp1),    w2  = fmaf(ro, K.B2, xp2);      \
    float z1  = fmaf(rc, ro*K.B1m2, w1), z2 = fmaf(rc, ro*K.B2m2, w2);  \
    tail2(z1, z2, rc, ro, C);                                           \
}while(0)

// one closed-loop step (x_in = h): z = W*h + C folded; dest <- new h (for preds)
#define CSTEP(dest) do{                                                 \
    float w1 = fmaf(ro, K.W1, K.C1), w2 = fmaf(ro, K.W2, K.C2);         \
    float z1 = fmaf(rc, ro*K.W1m2, w1), z2 = fmaf(rc, ro*K.W2m2, w2);   \
    tail2(z1, z2, rc, ro, C);                                           \
    float ro2 = ro + ro; (dest) = fmaf(-rc, ro2, ro);                   \
}while(0)

// stage a 32-row x 64-col chunk: 8 float4/lane, coalesced global reads
__device__ __forceinline__ void stage_issue32(const float* __restrict__ base,
                                              int rs, int col0, int lane, float4* v){
    const int r_lo = lane >> 4, c4 = lane & 15;
    #pragma unroll
    for (int j = 0; j < 8; ++j)
        v[j] = *(const float4*)(base + (size_t)(j*4 + r_lo) * rs + col0 + c4*4);
}
__device__ __forceinline__ void stage_write32(float* __restrict__ lds, int lane,
                                              const float4* v){
    const int r_lo = lane >> 4, c4 = lane & 15;
    #pragma unroll
    for (int j = 0; j < 8; ++j){
        float* p = lds + (j*4 + r_lo) * PAD + c4*4;   // rows 4B-aligned (PAD=65)
        p[0]=v[j].x; p[1]=v[j].y; p[2]=v[j].z; p[3]=v[j].w;
    }
}

__global__ __launch_bounds__(64) void lstm_chain_kernel(
    const float* __restrict__ x, const float* __restrict__ t,
    const float* __restrict__ h0, const float* __restrict__ c0,
    const float* __restrict__ w_ih, const float* __restrict__ w_hh,
    const float* __restrict__ b_ih, const float* __restrict__ b_hh,
    float* __restrict__ out)
{
    __shared__ float sb[2][CPB * PAD];   // x/t staging, double-buffered
    __shared__ float pb[CPB * PPAD];     // pred staging (16B-aligned rows)

    const int lane = threadIdx.x;
    const bool odd = lane & 1;
    const int ch   = lane >> 1;          // chain within block (0..31)
    const int b0   = blockIdx.x * CPB;

    LaneK K;
    {
        float bi = b_ih[0] + b_hh[0], bf = b_ih[1] + b_hh[1];
        float bg = b_ih[2] + b_hh[2], bo = b_ih[3] + b_hh[3];
        float Ai = -L2E*w_ih[0], Bi = -L2E*w_hh[0], Ci = -L2E*bi;
        float Af = -L2E*w_ih[1], Bf = -L2E*w_hh[1], Cf = -L2E*bf;
        float Ag = 2.0f*L2E*w_ih[2], Bg = 2.0f*L2E*w_hh[2], Cg = 2.0f*L2E*bg;
        float Ao = -L2E*w_ih[3], Bo = -L2E*w_hh[3], Co = -L2E*bo;
        K.A1 = odd ? Af : Ai;  K.B1 = odd ? Bf : Bi;  K.C1 = odd ? Cf : Ci;
        K.A2 = odd ? Ao : Ag;  K.B2 = odd ? Bo : Bg;  K.C2 = odd ? Co : Cg;
        K.W1 = K.A1 + K.B1;    K.W2 = K.A2 + K.B2;
        K.B1m2 = -2.0f*K.B1;   K.B2m2 = -2.0f*K.B2;
        K.W1m2 = -2.0f*K.W1;   K.W2m2 = -2.0f*K.W2;
    }

    // folded state: (rc=0, ro=h0) makes the first folded z bit-equal to
    // z = fma(h0, B, fma(x0, A, C))
    float rc = 0.0f;
    float ro = h0[b0 + ch];
    float C  = (2.0f * L2E) * c0[b0 + ch];

    const float* xbase = x + (size_t)b0 * T_IN;
    const float* tbase = t + (size_t)b0 * STEPS;

    // ---- open loop: 16 chunks of 64 steps ----
    { float4 stg[8]; stage_issue32(xbase, T_IN, 0, lane, stg); stage_write32(sb[0], lane, stg); }
    #pragma unroll 1
    for (int k = 0; k < T_IN / CH; ++k){
        float4 stg[8];
        if (k < T_IN/CH - 1) stage_issue32(xbase, T_IN, (k+1)*CH, lane, stg);
        const float* xrow = &sb[k & 1][ch * PAD];
        #pragma unroll 8
        for (int s = 0; s < CH; ++s){
            float xv = xrow[s];
            OSTEP(xv);
        }
        if (k < T_IN/CH - 1) stage_write32(sb[(k+1) & 1], lane, stg);
    }
    float h;
    { float ro2 = ro + ro; h = fmaf(-rc, ro2, ro); }   // h after open loop
    float xin = sb[1][ch * PAD + (CH - 1)];            // x[b,1023] (chunk 15 -> buf 1)

    // ---- closed loop: 8 chunks of 64 steps ----
    { float4 stg[8]; stage_issue32(tbase, STEPS, 0, lane, stg); stage_write32(sb[0], lane, stg); }
    float lacc = 0.0f;
    #pragma unroll 1
    for (int k = 0; k < STEPS / CH; ++k){
        float4 stg[8];
        if (k < STEPS/CH - 1) stage_issue32(tbase, STEPS, (k+1)*CH, lane, stg);
        float* prow = &pb[ch * PPAD];
        int q0 = 0;
        if (k == 0){
            // step 0 feeds x[b,1023] (direct form), steps 1..3 folded
            float a0, a1, a2, a3;
            {
                float z1 = fmaf(h, K.B1, fmaf(xin, K.A1, K.C1));
                float z2 = fmaf(h, K.B2, fmaf(xin, K.A2, K.C2));
                tail2(z1, z2, rc, ro, C);
                float ro2 = ro + ro; a0 = fmaf(-rc, ro2, ro);
            }
            CSTEP(a1); CSTEP(a2); CSTEP(a3);
            if (!odd) *(float4*)(prow) = make_float4(a0, a1, a2, a3);
            q0 = 1;
        }
        for (int q = q0; q < CH/4; ++q){
            float a0, a1, a2, a3;
            CSTEP(a0); CSTEP(a1); CSTEP(a2); CSTEP(a3);
            if (!odd) *(float4*)(&prow[q*4]) = make_float4(a0, a1, a2, a3);
        }
        // flush + fused loss: coalesced LDS reads, 64-dword global stores
        const float* trow = &sb[k & 1][0];
        float* obase = out + 1 + (size_t)b0 * STEPS + k * CH;
        #pragma unroll 4
        for (int r = 0; r < CPB; ++r){
            float p  = pb[r * PPAD + lane];
            float tv = trow[r * PAD + lane];
            float d  = p - tv;
            lacc = fmaf(d, d, lacc);
            obase[(size_t)r * STEPS + lane] = p;
        }
        if (k < STEPS/CH - 1) stage_write32(sb[(k+1) & 1], lane, stg);
    }

    // ---- loss: each (chain, step) counted exactly once -> scale 1/B ----
    #pragma unroll
    for (int off = 32; off > 0; off >>= 1)
        lacc += __shfl_down(lacc, off, 64);
    if (lane == 0)
        atomicAdd(out, lacc * (1.0f / (float)B_TOT));
}

extern "C" void kernel_launch(void* const* d_in, const int* in_sizes, int n_in,
                              void* d_out, int out_size, void* d_ws, size_t ws_size,
                              hipStream_t stream) {
    const float* x    = (const float*)d_in[0];
    const float* t    = (const float*)d_in[1];
    const float* h0   = (const float*)d_in[2];
    const float* c0   = (const float*)d_in[3];
    const float* w_ih = (const float*)d_in[4];
    const float* w_hh = (const float*)d_in[5];
    const float* b_ih = (const float*)d_in[6];
    const float* b_hh = (const float*)d_in[7];
    float* out = (float*)d_out;

    hipMemsetAsync(out, 0, sizeof(float), stream);

    lstm_chain_kernel<<<B_TOT / CPB, 64, 0, stream>>>(
        x, t, h0, c0, w_ih, w_hh, b_ih, b_hh, out);
}

// Round 3
// 315.022 us; speedup vs baseline: 1.0322x; 1.0322x over previous
//
#include <hip/hip_runtime.h>

// Hidden-size-1 LSTM, B=32768 chains, 1024 open + 512 closed steps.
// R6 = EXACT R3 (the measured-best 137us: 2 lanes/chain, 1024 waves =
// 1/SIMD, DPP pair-broadcasts, fused loss in flush) + ONE change:
//  - open-loop x reads prefetched one 8-step group ahead into registers.
//    R3 read xrow[s] per step (ds_read_b32, ~120cyc latency); with
//    unroll-8 the group's 8 loads issue at group top and the first use
//    stalls ~120cyc -> ~15 cyc/step over the 1024 open steps. Hoisting
//    group g+1's loads before group g's compute gives ~1700cyc of
//    latency cover. A/B disambiguates the stall model: if the ~90
//    stall-cyc/step is LDS (open loop), this wins ~5%; if it's trans
//    dep-latency, clean null -> chain-latency floor.
// Chain math is bit-identical to R3. sigma(z)=rcp(1+exp2(-L2E*z));
// tanh(z)=1-2*rcp(1+exp2(2*L2E*z)); c pre-scaled: C = 2*log2(e)*c.

#define L2E 1.44269504088896340736f
#define B_TOT 32768
#define T_IN 1024
#define STEPS 512
#define CPB 32          // chains per block (one wave, 2 lanes/chain)
#define CH 64           // chunk length in steps
#define PAD 65          // LDS row stride: bank = (chain + s) % 32

__device__ __forceinline__ float ex2(float x){ return __builtin_amdgcn_exp2f(x); }
__device__ __forceinline__ float rcp(float x){ return __builtin_amdgcn_rcpf(x); }
template<int CTRL>
__device__ __forceinline__ float qp(float v){
    // quad_perm broadcast: 0xA0 -> lanes {0,1}<-0,{2,3}<-2 (even pair member)
    //                      0xF5 -> lanes {0,1}<-1,{2,3}<-3 (odd pair member)
    return __int_as_float(__builtin_amdgcn_mov_dpp(__float_as_int(v), CTRL, 0xF, 0xF, true));
}

struct LaneK { float A1,B1,C1, A2,B2,C2, W1,W2; };

// even lane: z1 = i-gate (-L2E scale), z2 = g-gate (+2*L2E scale)
// odd  lane: z1 = f-gate,              z2 = o-gate
__device__ __forceinline__ void tail(float z1, float z2, float& h, float& C){
    float r1 = rcp(1.0f + ex2(z1));
    float r2 = rcp(1.0f + ex2(z2));
    float ri = qp<0xA0>(r1);      // sigma(zi)  (even member's r1)
    float rf = qp<0xF5>(r1);      // sigma(zf)  (odd member's r1)
    float rg = qp<0xA0>(r2);      // 1/(1+e^{2 zg})
    float ro = qp<0xF5>(r2);      // sigma(zo)
    float g2 = fmaf(rg, -4.0f * L2E, 2.0f * L2E);   // 2*L2E*tanh(g)
    C = fmaf(rf, C, ri * g2);                        // C = 2*L2E*c_new
    float e   = ex2(C);
    float ro2 = ro + ro;          // parallel with the rcp below
    float rc  = rcp(1.0f + e);
    h = fmaf(-rc, ro2, ro);       // h = ro*(1-2rc)
}

// stage a 32-row x 64-col chunk: 8 float4/lane, coalesced global reads
__device__ __forceinline__ void stage_issue32(const float* __restrict__ base,
                                              int rs, int col0, int lane, float4* v){
    const int r_lo = lane >> 4, c4 = lane & 15;
    #pragma unroll
    for (int j = 0; j < 8; ++j)
        v[j] = *(const float4*)(base + (size_t)(j*4 + r_lo) * rs + col0 + c4*4);
}
__device__ __forceinline__ void stage_write32(float* __restrict__ lds, int lane,
                                              const float4* v){
    const int r_lo = lane >> 4, c4 = lane & 15;
    #pragma unroll
    for (int j = 0; j < 8; ++j){
        float* p = lds + (j*4 + r_lo) * PAD + c4*4;   // rows 4B-aligned (PAD=65)
        p[0]=v[j].x; p[1]=v[j].y; p[2]=v[j].z; p[3]=v[j].w;
    }
}

__global__ __launch_bounds__(64) void lstm_chain_kernel(
    const float* __restrict__ x, const float* __restrict__ t,
    const float* __restrict__ h0, const float* __restrict__ c0,
    const float* __restrict__ w_ih, const float* __restrict__ w_hh,
    const float* __restrict__ b_ih, const float* __restrict__ b_hh,
    float* __restrict__ out)
{
    __shared__ float sb[2][CPB * PAD];   // x/t staging, double-buffered
    __shared__ float pb[CPB * PAD];      // pred staging

    const int lane = threadIdx.x;
    const bool odd = lane & 1;
    const int ch   = lane >> 1;          // chain within block (0..31)
    const int b0   = blockIdx.x * CPB;

    LaneK K;
    {
        float bi = b_ih[0] + b_hh[0], bf = b_ih[1] + b_hh[1];
        float bg = b_ih[2] + b_hh[2], bo = b_ih[3] + b_hh[3];
        float Ai = -L2E*w_ih[0], Bi = -L2E*w_hh[0], Ci = -L2E*bi;
        float Af = -L2E*w_ih[1], Bf = -L2E*w_hh[1], Cf = -L2E*bf;
        float Ag = 2.0f*L2E*w_ih[2], Bg = 2.0f*L2E*w_hh[2], Cg = 2.0f*L2E*bg;
        float Ao = -L2E*w_ih[3], Bo = -L2E*w_hh[3], Co = -L2E*bo;
        K.A1 = odd ? Af : Ai;  K.B1 = odd ? Bf : Bi;  K.C1 = odd ? Cf : Ci;
        K.A2 = odd ? Ao : Ag;  K.B2 = odd ? Bo : Bg;  K.C2 = odd ? Co : Cg;
        K.W1 = K.A1 + K.B1;    K.W2 = K.A2 + K.B2;    // closed loop: x_in = h
    }

    float h = h0[b0 + ch];
    float C = (2.0f * L2E) * c0[b0 + ch];

    const float* xbase = x + (size_t)b0 * T_IN;
    const float* tbase = t + (size_t)b0 * STEPS;

    // ---- open loop: 16 chunks of 64 steps ----
    { float4 stg[8]; stage_issue32(xbase, T_IN, 0, lane, stg); stage_write32(sb[0], lane, stg); }
    #pragma unroll 1
    for (int k = 0; k < T_IN / CH; ++k){
        float4 stg[8];
        if (k < T_IN/CH - 1) stage_issue32(xbase, T_IN, (k+1)*CH, lane, stg);
        const float* xrow = &sb[k & 1][ch * PAD];
        // register prefetch: group g+1's 8 x-values load while group g computes
        float cur[8], nxt[8];
        #pragma unroll
        for (int j = 0; j < 8; ++j) cur[j] = xrow[j];
        #pragma unroll
        for (int g = 0; g < 8; ++g){
            if (g < 7){
                #pragma unroll
                for (int j = 0; j < 8; ++j) nxt[j] = xrow[(g+1)*8 + j];
            }
            #pragma unroll
            for (int s = 0; s < 8; ++s){
                float xv = cur[s];
                // x-side FMA off the h-critical path
                float z1 = fmaf(h, K.B1, fmaf(xv, K.A1, K.C1));
                float z2 = fmaf(h, K.B2, fmaf(xv, K.A2, K.C2));
                tail(z1, z2, h, C);
            }
            if (g < 7){
                #pragma unroll
                for (int j = 0; j < 8; ++j) cur[j] = nxt[j];
            }
        }
        if (k < T_IN/CH - 1) stage_write32(sb[(k+1) & 1], lane, stg);
    }
    float xin = sb[1][ch * PAD + (CH - 1)];   // x[b,1023] (chunk 15 -> buf 1)

    // ---- closed loop: 8 chunks of 64 steps ----
    { float4 stg[8]; stage_issue32(tbase, STEPS, 0, lane, stg); stage_write32(sb[0], lane, stg); }
    float lacc = 0.0f;
    #pragma unroll 1
    for (int k = 0; k < STEPS / CH; ++k){
        float4 stg[8];
        if (k < STEPS/CH - 1) stage_issue32(tbase, STEPS, (k+1)*CH, lane, stg);
        float* prow = &pb[ch * PAD];
        if (k == 0){
            // first closed step feeds x[b,1023], not h
            tail(fmaf(h, K.B1, fmaf(xin, K.A1, K.C1)),
                 fmaf(h, K.B2, fmaf(xin, K.A2, K.C2)), h, C);
            prow[0] = h;
            #pragma unroll 8
            for (int s = 1; s < CH; ++s){
                tail(fmaf(h, K.W1, K.C1), fmaf(h, K.W2, K.C2), h, C);
                prow[s] = h;
            }
        } else {
            #pragma unroll 8
            for (int s = 0; s < CH; ++s){
                tail(fmaf(h, K.W1, K.C1), fmaf(h, K.W2, K.C2), h, C);
                prow[s] = h;
            }
        }
        // flush + fused loss: coalesced LDS reads (bank = (r+lane)%32),
        // 64 consecutive dwords per global store instruction
        const float* trow = &sb[k & 1][0];
        float* obase = out + 1 + (size_t)b0 * STEPS + k * CH;
        #pragma unroll 4
        for (int r = 0; r < CPB; ++r){
            float p  = pb[r * PAD + lane];
            float tv = trow[r * PAD + lane];
            float d  = p - tv;
            lacc = fmaf(d, d, lacc);
            obase[(size_t)r * STEPS + lane] = p;
        }
        if (k < STEPS/CH - 1) stage_write32(sb[(k+1) & 1], lane, stg);
    }

    // ---- loss: each (chain, step) counted exactly once -> scale 1/B ----
    #pragma unroll
    for (int off = 32; off > 0; off >>= 1)
        lacc += __shfl_down(lacc, off, 64);
    if (lane == 0)
        atomicAdd(out, lacc * (1.0f / (float)B_TOT));
}

extern "C" void kernel_launch(void* const* d_in, const int* in_sizes, int n_in,
                              void* d_out, int out_size, void* d_ws, size_t ws_size,
                              hipStream_t stream) {
    const float* x    = (const float*)d_in[0];
    const float* t    = (const float*)d_in[1];
    const float* h0   = (const float*)d_in[2];
    const float* c0   = (const float*)d_in[3];
    const float* w_ih = (const float*)d_in[4];
    const float* w_hh = (const float*)d_in[5];
    const float* b_ih = (const float*)d_in[6];
    const float* b_hh = (const float*)d_in[7];
    float* out = (float*)d_out;

    hipMemsetAsync(out, 0, sizeof(float), stream);

    lstm_chain_kernel<<<B_TOT / CPB, 64, 0, stream>>>(
        x, t, h0, c0, w_ih, w_hh, b_ih, b_hh, out);
}